// Round 6
// baseline (340.896 us; speedup 1.0000x reference)
//
#include <hip/hip_runtime.h>

#define RED_THREADS 512

// ---------------- DPP wave64 funnel reduction (verified R5) ----------------
template <int Ctrl, int RowMask, int BankMask, bool BoundZero>
__device__ __forceinline__ float dpp_add(float x)
{
    int xi = __builtin_bit_cast(int, x);
    int yi = __builtin_amdgcn_update_dpp(0, xi, Ctrl, RowMask, BankMask,
                                         BoundZero);
    return x + __builtin_bit_cast(float, yi);
}

__device__ __forceinline__ float wave_sum_to_lane63(float x)
{
    x = dpp_add<0x111, 0xf, 0xf, true >(x);   // row_shr:1
    x = dpp_add<0x112, 0xf, 0xf, true >(x);   // row_shr:2
    x = dpp_add<0x114, 0xf, 0xf, true >(x);   // row_shr:4
    x = dpp_add<0x118, 0xf, 0xf, true >(x);   // row_shr:8
    x = dpp_add<0x142, 0xa, 0xf, false>(x);   // row_bcast:15 -> rows 1,3
    x = dpp_add<0x143, 0xc, 0xf, false>(x);   // row_bcast:31 -> rows 2,3
    return x;                                  // lane 63 = full-wave sum
}

// ---------------- L1-bypass (sc0) asm load stage ----------------
// 7 dword loads per point (v.xyz, vn.xyz, sr), all 4-B aligned, agent-scope
// (sc0 = read from L2, no L1 allocation / no L1 MSHR slot). Volatile asm
// fixes issue order; the waitcnt asm takes the stage registers as "+v"
// operands so consumers are data-dependent on the wait (rule-18-safe).
#define PRELOAD(S, av, aq, as)                                               \
    asm volatile("global_load_dword %0, %1, off sc0"          : "=v"(S##vx) : "v"(av)); \
    asm volatile("global_load_dword %0, %1, off offset:4 sc0" : "=v"(S##vy) : "v"(av)); \
    asm volatile("global_load_dword %0, %1, off offset:8 sc0" : "=v"(S##vz) : "v"(av)); \
    asm volatile("global_load_dword %0, %1, off sc0"          : "=v"(S##nx) : "v"(aq)); \
    asm volatile("global_load_dword %0, %1, off offset:4 sc0" : "=v"(S##ny) : "v"(aq)); \
    asm volatile("global_load_dword %0, %1, off offset:8 sc0" : "=v"(S##nz) : "v"(aq)); \
    asm volatile("global_load_dword %0, %1, off sc0"          : "=v"(S##s ) : "v"(as));

#define WAITS(S, CNT)                                                        \
    asm volatile("s_waitcnt vmcnt(" CNT ")"                                  \
                 : "+v"(S##vx), "+v"(S##vy), "+v"(S##vz),                    \
                   "+v"(S##nx), "+v"(S##ny), "+v"(S##nz), "+v"(S##s));

// Consume one ready stage: quartic weight, weighted dot, DPP reduce,
// accumulate sdf^2 (meaningful in lane 63 only).
#define CONSUME(S, PT)                                                       \
    {                                                                        \
        const float* pc = points + (size_t)(PT) * 3;                         \
        const float px = pc[0], py = pc[1], pz = pc[2];                      \
        const float dx = px - S##vx;                                         \
        const float dy = py - S##vy;                                         \
        const float dz = pz - S##vz;                                         \
        const float d2 = dx * dx + dy * dy + dz * dz;                        \
        const float wq = 1.0f - d2 / S##s;                                   \
        const float w2 = wq * wq;                                            \
        const float phi = (d2 < S##s) ? (w2 * w2) : 1e-18f;                  \
        const float dot = S##nx * dx + S##ny * dy + S##nz * dz;              \
        float num = lk ? (phi * dot) : 0.f;                                  \
        float den = lk ? phi : 0.f;                                          \
        num = wave_sum_to_lane63(num);                                       \
        den = wave_sum_to_lane63(den);                                       \
        const float sdf = num / den;                                         \
        const float s2  = sdf * sdf;                                         \
        if ((PT) < P) acc0 += s2; else acc1 += s2;                           \
    }

// Persistent-wave SDF kernel; two-stage asm pipeline with counted vmcnt and
// L1-bypass loads. Lanes 60..63 clamped to neighbor 59 (dup loads, masked at
// compute) so all loads are unconditional; the final half-iteration prefetch
// is address-clamped to a valid point (data unused).
__global__ __launch_bounds__(256) void sdf_main(
    const float* __restrict__ points,
    const float* __restrict__ v,
    const float* __restrict__ vn,
    const float* __restrict__ sr,
    float* __restrict__ ws,
    int NP, int P, int totalWaves, int slots, int slotStride)
{
    constexpr int K = 60;
    const int lane  = threadIdx.x & 63;
    const int wid   = blockIdx.x * 4 + (threadIdx.x >> 6);
    const bool lk   = lane < K;
    const int laneK = lk ? lane : (K - 1);
    const int stride = totalWaves;

    int pt = wid;
    if (pt >= NP) return;

    float S0vx, S0vy, S0vz, S0nx, S0ny, S0nz, S0s;
    float S1vx, S1vy, S1vz, S1nx, S1ny, S1nz, S1s;
    float acc0 = 0.f, acc1 = 0.f;

    // addresses for a given point index
    #define ADDRS(PTC, AV, AQ, AS)                                           \
        const float* AV = v  + (size_t)(PTC) * 180 + 3 * laneK;              \
        const float* AQ = vn + (size_t)(PTC) * 180 + 3 * laneK;              \
        const float* AS = sr + (size_t)(PTC) * 60  + laneK;

    // ---- prologue: stage S0 <- point wid ----
    {
        ADDRS(pt, av, aq, as);
        PRELOAD(S0, av, aq, as);
    }

    for (;;) {
        // ---- half A: prefetch S1 <- pt+stride, consume S0 @ pt ----
        {
            const int ptn = pt + stride;
            const int ptc = (ptn < NP) ? ptn : (NP - 1);   // clamped dummy ok
            ADDRS(ptc, av, aq, as);
            PRELOAD(S1, av, aq, as);
            WAITS(S0, "7");
            CONSUME(S0, pt);
            if (ptn >= NP) break;
            pt = ptn;
        }
        // ---- half B: prefetch S0 <- pt+stride, consume S1 @ pt ----
        {
            const int ptn = pt + stride;
            const int ptc = (ptn < NP) ? ptn : (NP - 1);
            ADDRS(ptc, av, aq, as);
            PRELOAD(S0, av, aq, as);
            WAITS(S1, "7");
            CONSUME(S1, pt);
            if (ptn >= NP) break;
            pt = ptn;
        }
    }

    // drain any dummy prefetch still in flight before exiting
    asm volatile("s_waitcnt vmcnt(0)" ::: "memory");

    if (lane == 63) {   // reduction result lives in lane 63
        const int slot = wid & (slots - 1);
        atomicAdd(&ws[slot * slotStride + 0], acc0);
        atomicAdd(&ws[slot * slotStride + 1], acc1);
    }
    #undef ADDRS
}

// Single-block final reduction over `slots` partial sums per batch index.
__global__ __launch_bounds__(RED_THREADS) void sdf_reduce(
    const float* __restrict__ ws, float* __restrict__ out,
    int N, int slots, int slotStride)
{
    __shared__ float sm0[RED_THREADS];
    __shared__ float sm1[RED_THREADS];
    const int tid = threadIdx.x;
    float a = 0.f, b = 0.f;
    for (int s = tid; s < slots; s += RED_THREADS) {
        a += ws[s * slotStride + 0];
        if (N > 1) b += ws[s * slotStride + 1];
    }
    sm0[tid] = a;
    sm1[tid] = b;
    __syncthreads();
    #pragma unroll
    for (int s = RED_THREADS / 2; s >= 1; s >>= 1) {
        if (tid < s) {
            sm0[tid] += sm0[tid + s];
            sm1[tid] += sm1[tid + s];
        }
        __syncthreads();
    }
    if (tid == 0) {
        out[0] = sm0[0];
        if (N > 1) out[1] = sm1[0];
    }
}

extern "C" void kernel_launch(void* const* d_in, const int* in_sizes, int n_in,
                              void* d_out, int out_size, void* d_ws, size_t ws_size,
                              hipStream_t stream) {
    const float* points = (const float*)d_in[0];
    const float* v      = (const float*)d_in[1];
    const float* vn     = (const float*)d_in[2];
    const float* sr     = (const float*)d_in[3];
    float* out = (float*)d_out;
    float* ws  = (float*)d_ws;

    const int NP = in_sizes[0] / 3;        // N*P total points (200000)
    const int N  = out_size;               // 2
    const int P  = NP / N;                 // 100000

    int slots = 512, slotStride = 16;      // 32 KiB: one cache line per slot
    if (ws_size < (size_t)(slots * slotStride * sizeof(float))) {
        slots = 256; slotStride = 2;       // 2 KiB fallback
    }

    (void)hipMemsetAsync(ws, 0, (size_t)slots * slotStride * sizeof(float),
                         stream);

    // Persistent grid: 2048 blocks x 4 waves = 8192 waves (32 waves/CU).
    int blocks = (NP + 3) / 4;
    if (blocks > 2048) blocks = 2048;
    const int totalWaves = blocks * 4;

    sdf_main<<<blocks, 256, 0, stream>>>(points, v, vn, sr, ws, NP, P,
                                         totalWaves, slots, slotStride);
    sdf_reduce<<<1, RED_THREADS, 0, stream>>>(ws, out, N, slots, slotStride);
}